// Round 2
// baseline (2859.368 us; speedup 1.0000x reference)
//
#include <hip/hip_runtime.h>
#include <hip/hip_bf16.h>
#include <math.h>

#define L_SEQ   2048
#define M_ROWS  4096            // B*L
#define DPROJ   4384
#define DINNER  2048
#define CONVDIM 2304
#define NST     128
#define NH      32

// ---------------------------------------------------------------------------
// GEMM (f32): C[M][N] = A[M][K] @ B[N][K]^T, optional epilogue add of
// addsrc[M][add_ld]. Per-dir A/B pointers, C offset. 64x64x16 tiles,
// 256 threads, 4x4 per-thread microtile.
// ---------------------------------------------------------------------------
__global__ __launch_bounds__(256) void gemm_f32(
    const float* __restrict__ A0, const float* __restrict__ A1, int lda,
    const float* __restrict__ B0, const float* __restrict__ B1,
    float* __restrict__ C, long long c_dir_off, int ldc,
    const float* __restrict__ addsrc, int add_ld,
    int M, int N, int K)
{
    const int dir = blockIdx.z;
    const float* __restrict__ A = dir ? A1 : A0;
    const float* __restrict__ B = dir ? B1 : B0;
    float* __restrict__ Cp = C + (size_t)dir * (size_t)c_dir_off;

    const int m0 = blockIdx.y * 64;
    const int n0 = blockIdx.x * 64;

    __shared__ float As[16][68];   // [k][m], +4 pad
    __shared__ float Bs[16][68];   // [k][n]

    const int tid  = threadIdx.x;
    const int tx   = tid & 15;
    const int ty   = tid >> 4;
    const int srow = tid >> 2;          // 0..63
    const int scol = (tid & 3) << 2;    // 0,4,8,12

    float acc[4][4];
#pragma unroll
    for (int i = 0; i < 4; ++i)
#pragma unroll
        for (int j = 0; j < 4; ++j) acc[i][j] = 0.f;

    for (int k0 = 0; k0 < K; k0 += 16) {
        float4 av = *(const float4*)(A + (size_t)(m0 + srow) * lda + k0 + scol);
        float4 bv = make_float4(0.f, 0.f, 0.f, 0.f);
        const int bn = n0 + srow;
        if (bn < N) bv = *(const float4*)(B + (size_t)bn * K + k0 + scol);

        __syncthreads();
        As[scol + 0][srow] = av.x; As[scol + 1][srow] = av.y;
        As[scol + 2][srow] = av.z; As[scol + 3][srow] = av.w;
        Bs[scol + 0][srow] = bv.x; Bs[scol + 1][srow] = bv.y;
        Bs[scol + 2][srow] = bv.z; Bs[scol + 3][srow] = bv.w;
        __syncthreads();

#pragma unroll
        for (int k = 0; k < 16; ++k) {
            const float4 a4 = *(const float4*)&As[k][ty << 2];
            const float4 b4 = *(const float4*)&Bs[k][tx << 2];
            const float a[4] = {a4.x, a4.y, a4.z, a4.w};
            const float b[4] = {b4.x, b4.y, b4.z, b4.w};
#pragma unroll
            for (int i = 0; i < 4; ++i)
#pragma unroll
                for (int j = 0; j < 4; ++j)
                    acc[i][j] = fmaf(a[i], b[j], acc[i][j]);
        }
    }

#pragma unroll
    for (int i = 0; i < 4; ++i) {
        const int row = m0 + (ty << 2) + i;
#pragma unroll
        for (int j = 0; j < 4; ++j) {
            const int col = n0 + (tx << 2) + j;
            if (col < N) {
                float v = acc[i][j];
                if (addsrc) v += addsrc[(size_t)row * add_ld + col];
                Cp[(size_t)row * ldc + col] = v;
            }
        }
    }
}

// ---------------------------------------------------------------------------
// Depthwise causal conv(4) + SiLU on xBC slice of zxbcdt; softplus(dt);
// dA = exp(dt * -exp(A_log)). Bwd direction = tap reversal at original index.
// xs written as bf16.
// ---------------------------------------------------------------------------
__global__ __launch_bounds__(256) void conv_dt_kernel(
    const float* __restrict__ zx,
    const float* __restrict__ cw0, const float* __restrict__ cw1,
    const float* __restrict__ cb0, const float* __restrict__ cb1,
    const float* __restrict__ dtbias0, const float* __restrict__ dtbias1,
    const float* __restrict__ Alog0, const float* __restrict__ Alog1,
    __hip_bfloat16* __restrict__ xs, float* __restrict__ Bcb, float* __restrict__ Ccb,
    float* __restrict__ dtb, float* __restrict__ dab)
{
    const int dir = blockIdx.y;
    const int row = blockIdx.x;          // b*L + l
    const int b = row >> 11;
    const int l = row & (L_SEQ - 1);

    const float* __restrict__ cw = dir ? cw1 : cw0;
    const float* __restrict__ cb = dir ? cb1 : cb0;
    const float* __restrict__ dtbias = dir ? dtbias1 : dtbias0;
    const float* __restrict__ Alog = dir ? Alog1 : Alog0;
    const float* __restrict__ zbase = zx + (size_t)dir * M_ROWS * DPROJ;
    const size_t orow = (size_t)(dir * M_ROWS + row);

    for (int c = threadIdx.x; c < CONVDIM; c += 256) {
        float acc = cb[c];
        const float w0 = cw[c * 4 + 0], w1 = cw[c * 4 + 1];
        const float w2 = cw[c * 4 + 2], w3 = cw[c * 4 + 3];
        if (dir == 0) {
#pragma unroll
            for (int k = 0; k < 4; ++k) {
                const int p = l - 3 + k;
                if (p >= 0) {
                    const float wv = (k == 0) ? w0 : (k == 1) ? w1 : (k == 2) ? w2 : w3;
                    acc += zbase[(size_t)(b * L_SEQ + p) * DPROJ + DINNER + c] * wv;
                }
            }
        } else {
#pragma unroll
            for (int k = 0; k < 4; ++k) {
                const int p = l + 3 - k;
                if (p < L_SEQ) {
                    const float wv = (k == 0) ? w0 : (k == 1) ? w1 : (k == 2) ? w2 : w3;
                    acc += zbase[(size_t)(b * L_SEQ + p) * DPROJ + DINNER + c] * wv;
                }
            }
        }
        const float s = acc / (1.f + expf(-acc));   // SiLU
        if (c < DINNER)            xs[orow * DINNER + c] = __float2bfloat16(s);
        else if (c < DINNER + NST) Bcb[orow * NST + (c - DINNER)] = s;
        else                       Ccb[orow * NST + (c - DINNER - NST)] = s;
    }

    if (threadIdx.x < NH) {
        const int h = threadIdx.x;
        const float v = zbase[(size_t)row * DPROJ + (DINNER + CONVDIM) + h] + dtbias[h];
        const float sp = (v > 20.f) ? v : log1pf(expf(v));
        const float a = -expf(Alog[h]);
        dtb[orow * NH + h] = sp;
        dab[orow * NH + h] = expf(sp * a);
    }
}

// ---------------------------------------------------------------------------
// Sequential SSM scan + D-skip. One block per (dir, b, h): 512 threads, each
// owns h[p][n0..n0+15]. Double-buffered LDS with register prefetch. y written
// into the (dead) xBC slice of zx: stride DPROJ, offset DINNER.
// ---------------------------------------------------------------------------
__global__ __launch_bounds__(512) void scan_kernel(
    const __hip_bfloat16* __restrict__ xs, const float* __restrict__ Bcb,
    const float* __restrict__ Ccb, const float* __restrict__ dtb,
    const float* __restrict__ dab,
    const float* __restrict__ D0, const float* __restrict__ D1,
    float* __restrict__ zx)
{
    const int dir = blockIdx.y;
    const int bh = blockIdx.x;
    const int b = bh >> 5;
    const int h = bh & 31;
    const int tid = threadIdx.x;
    const int p = tid >> 3;
    const int g = tid & 7;
    const int n0 = g << 4;
    const float Dv = (dir ? D1 : D0)[h];

    __shared__ float sx[2][64];
    __shared__ float sB[2][NST];
    __shared__ float sC[2][NST];
    __shared__ float sS[2][2];   // [buf][0]=dt, [buf][1]=dA

    float hst[16];
#pragma unroll
    for (int i = 0; i < 16; ++i) hst[i] = 0.f;

    const size_t dbase = (size_t)(dir * M_ROWS + b * L_SEQ);
    float* __restrict__ ybase = zx + (size_t)dir * M_ROWS * DPROJ + DINNER;

    {
        const int l = dir ? (L_SEQ - 1) : 0;
        const size_t r = dbase + l;
        if (tid < 64)        sx[0][tid] = __bfloat162float(xs[r * DINNER + h * 64 + tid]);
        else if (tid < 192)  sB[0][tid - 64] = Bcb[r * NST + (tid - 64)];
        else if (tid < 320)  sC[0][tid - 192] = Ccb[r * NST + (tid - 192)];
        else if (tid == 320) sS[0][0] = dtb[r * NH + h];
        else if (tid == 321) sS[0][1] = dab[r * NH + h];
    }
    __syncthreads();

    for (int t = 0; t < L_SEQ; ++t) {
        const int cur = t & 1, nxt = cur ^ 1;

        float pv = 0.f;
        const bool havenext = (t + 1 < L_SEQ);
        if (havenext) {
            const int ln = dir ? (L_SEQ - 2 - t) : (t + 1);
            const size_t r = dbase + ln;
            if (tid < 64)        pv = __bfloat162float(xs[r * DINNER + h * 64 + tid]);
            else if (tid < 192)  pv = Bcb[r * NST + (tid - 64)];
            else if (tid < 320)  pv = Ccb[r * NST + (tid - 192)];
            else if (tid == 320) pv = dtb[r * NH + h];
            else if (tid == 321) pv = dab[r * NH + h];
        }

        const float dtv = sS[cur][0];
        const float dav = sS[cur][1];
        const float xv  = sx[cur][p];
        const float sxv = dtv * xv;
        float acc = 0.f;
        const float* __restrict__ Bp = &sB[cur][n0];
        const float* __restrict__ Cp = &sC[cur][n0];
#pragma unroll
        for (int j = 0; j < 16; ++j) {
            hst[j] = fmaf(hst[j], dav, sxv * Bp[j]);
            acc = fmaf(hst[j], Cp[j], acc);
        }
        acc += __shfl_xor(acc, 1);
        acc += __shfl_xor(acc, 2);
        acc += __shfl_xor(acc, 4);
        if (g == 0) {
            const int l = dir ? (L_SEQ - 1 - t) : t;
            ybase[(size_t)(b * L_SEQ + l) * DPROJ + h * 64 + p] = acc + Dv * xv;
        }

        if (havenext) {
            if (tid < 64)        sx[nxt][tid] = pv;
            else if (tid < 192)  sB[nxt][tid - 64] = pv;
            else if (tid < 320)  sC[nxt][tid - 192] = pv;
            else if (tid == 320) sS[nxt][0] = pv;
            else if (tid == 321) sS[nxt][1] = pv;
        }
        __syncthreads();
    }
}

// ---------------------------------------------------------------------------
// y = y * silu(z); RMSNorm(2048) * norm_w. In-place on the y slice of zx
// (offset DINNER, stride DPROJ). One block per (dir, row).
// ---------------------------------------------------------------------------
__global__ __launch_bounds__(256) void gatenorm_kernel(
    float* __restrict__ zx,
    const float* __restrict__ nw0, const float* __restrict__ nw1)
{
    const int dir = blockIdx.y;
    const int row = blockIdx.x;
    const float* __restrict__ nw = dir ? nw1 : nw0;
    float* __restrict__ rowp = zx + (size_t)dir * M_ROWS * DPROJ + (size_t)row * DPROJ;
    const int tid = threadIdx.x;

    float gv[8];
    float ss = 0.f;
#pragma unroll
    for (int i = 0; i < 8; ++i) {
        const int c = i * 256 + tid;
        const float yv = rowp[DINNER + c];
        const float zv = rowp[c];
        const float gg = yv * (zv / (1.f + expf(-zv)));
        gv[i] = gg;
        ss = fmaf(gg, gg, ss);
    }
#pragma unroll
    for (int off = 1; off < 64; off <<= 1) ss += __shfl_xor(ss, off);
    __shared__ float red[4];
    if ((tid & 63) == 0) red[tid >> 6] = ss;
    __syncthreads();
    const float total = red[0] + red[1] + red[2] + red[3];
    const float rs = rsqrtf(total * (1.f / (float)DINNER) + 1e-5f);
#pragma unroll
    for (int i = 0; i < 8; ++i) {
        const int c = i * 256 + tid;
        rowp[DINNER + c] = gv[i] * rs * nw[c];
    }
}

// ---------------------------------------------------------------------------
extern "C" void kernel_launch(void* const* d_in, const int* in_sizes, int n_in,
                              void* d_out, int out_size, void* d_ws, size_t ws_size,
                              hipStream_t stream)
{
    (void)in_sizes; (void)n_in; (void)out_size; (void)ws_size;
    const float* x        = (const float*)d_in[0];
    const float* f_in_w   = (const float*)d_in[1];
    const float* f_conv_w = (const float*)d_in[2];
    const float* f_conv_b = (const float*)d_in[3];
    const float* f_dtbias = (const float*)d_in[4];
    const float* f_Alog   = (const float*)d_in[5];
    const float* f_D      = (const float*)d_in[6];
    const float* f_nw     = (const float*)d_in[7];
    const float* f_out_w  = (const float*)d_in[8];
    const float* b_in_w   = (const float*)d_in[9];
    const float* b_conv_w = (const float*)d_in[10];
    const float* b_conv_b = (const float*)d_in[11];
    const float* b_dtbias = (const float*)d_in[12];
    const float* b_Alog   = (const float*)d_in[13];
    const float* b_D      = (const float*)d_in[14];
    const float* b_nw     = (const float*)d_in[15];
    const float* b_out_w  = (const float*)d_in[16];

    // Workspace layout (187.7 MB total):
    //   zx : 2*M*4384 f32 (143.7 MB); y aliased into cols [2048,4096) after conv
    //   xs : 2*M*2048 bf16 (33.6 MB)
    //   B,C: 2*M*128 f32 each (8.4 MB); dt,dA: 2*M*32 f32 each (2.1 MB)
    float* ws  = (float*)d_ws;
    float* zx  = ws;
    __hip_bfloat16* xs = (__hip_bfloat16*)(zx + (size_t)2 * M_ROWS * DPROJ);
    float* Bcb = (float*)(xs + (size_t)2 * M_ROWS * DINNER);
    float* Ccb = Bcb + (size_t)2 * M_ROWS * NST;
    float* dtb = Ccb + (size_t)2 * M_ROWS * NST;
    float* dab = dtb + (size_t)2 * M_ROWS * NH;

    // 1) in_proj: zx[dir] = x @ in_w[dir]^T   (M=4096, N=4384, K=512)
    gemm_f32<<<dim3(69, 64, 2), 256, 0, stream>>>(
        x, x, 512, f_in_w, b_in_w,
        zx, (long long)M_ROWS * DPROJ, DPROJ,
        nullptr, 0, M_ROWS, DPROJ, 512);

    // 2) conv + SiLU + dt/dA
    conv_dt_kernel<<<dim3(M_ROWS, 2), 256, 0, stream>>>(
        zx, f_conv_w, b_conv_w, f_conv_b, b_conv_b,
        f_dtbias, b_dtbias, f_Alog, b_Alog,
        xs, Bcb, Ccb, dtb, dab);

    // 3) sequential SSM scan + D-skip; y -> zx cols [2048,4096)
    scan_kernel<<<dim3(64, 2), 512, 0, stream>>>(
        xs, Bcb, Ccb, dtb, dab, f_D, b_D, zx);

    // 4) gate + RMSNorm in place on y slice
    gatenorm_kernel<<<dim3(M_ROWS, 2), 256, 0, stream>>>(zx, f_nw, b_nw);

    // 5) out_proj + residual + concat: d_out[row][dir*512 + o]
    gemm_f32<<<dim3(8, 64, 2), 256, 0, stream>>>(
        zx + DINNER, zx + (size_t)M_ROWS * DPROJ + DINNER, DPROJ,
        f_out_w, b_out_w,
        (float*)d_out, 512, 1024,
        x, 512, M_ROWS, 512, DINNER);
}

// Round 3
// 1589.023 us; speedup vs baseline: 1.7995x; 1.7995x over previous
//
#include <hip/hip_runtime.h>
#include <hip/hip_bf16.h>
#include <math.h>

#define L_SEQ   2048
#define M_ROWS  4096            // B*L
#define DPROJ   4384
#define DINNER  2048
#define CONVDIM 2304
#define NST     128
#define NH      32
#define SEGLEN  256
#define NSEG    8

// ---------------------------------------------------------------------------
// GEMM (f32): C[M][N] = A[M][K] @ B[N][K]^T (+ optional addsrc epilogue).
// 64x64x16 tiles, 256 threads, 4x4 microtile.
// ---------------------------------------------------------------------------
__global__ __launch_bounds__(256) void gemm_f32(
    const float* __restrict__ A0, const float* __restrict__ A1, int lda,
    const float* __restrict__ B0, const float* __restrict__ B1,
    float* __restrict__ C, long long c_dir_off, int ldc,
    const float* __restrict__ addsrc, int add_ld,
    int M, int N, int K)
{
    const int dir = blockIdx.z;
    const float* __restrict__ A = dir ? A1 : A0;
    const float* __restrict__ B = dir ? B1 : B0;
    float* __restrict__ Cp = C + (size_t)dir * (size_t)c_dir_off;

    const int m0 = blockIdx.y * 64;
    const int n0 = blockIdx.x * 64;

    __shared__ float As[16][68];
    __shared__ float Bs[16][68];

    const int tid  = threadIdx.x;
    const int tx   = tid & 15;
    const int ty   = tid >> 4;
    const int srow = tid >> 2;
    const int scol = (tid & 3) << 2;

    float acc[4][4];
#pragma unroll
    for (int i = 0; i < 4; ++i)
#pragma unroll
        for (int j = 0; j < 4; ++j) acc[i][j] = 0.f;

    for (int k0 = 0; k0 < K; k0 += 16) {
        float4 av = *(const float4*)(A + (size_t)(m0 + srow) * lda + k0 + scol);
        float4 bv = make_float4(0.f, 0.f, 0.f, 0.f);
        const int bn = n0 + srow;
        if (bn < N) bv = *(const float4*)(B + (size_t)bn * K + k0 + scol);

        __syncthreads();
        As[scol + 0][srow] = av.x; As[scol + 1][srow] = av.y;
        As[scol + 2][srow] = av.z; As[scol + 3][srow] = av.w;
        Bs[scol + 0][srow] = bv.x; Bs[scol + 1][srow] = bv.y;
        Bs[scol + 2][srow] = bv.z; Bs[scol + 3][srow] = bv.w;
        __syncthreads();

#pragma unroll
        for (int k = 0; k < 16; ++k) {
            const float4 a4 = *(const float4*)&As[k][ty << 2];
            const float4 b4 = *(const float4*)&Bs[k][tx << 2];
            const float a[4] = {a4.x, a4.y, a4.z, a4.w};
            const float b[4] = {b4.x, b4.y, b4.z, b4.w};
#pragma unroll
            for (int i = 0; i < 4; ++i)
#pragma unroll
                for (int j = 0; j < 4; ++j)
                    acc[i][j] = fmaf(a[i], b[j], acc[i][j]);
        }
    }

#pragma unroll
    for (int i = 0; i < 4; ++i) {
        const int row = m0 + (ty << 2) + i;
#pragma unroll
        for (int j = 0; j < 4; ++j) {
            const int col = n0 + (tx << 2) + j;
            if (col < N) {
                float v = acc[i][j];
                if (addsrc) v += addsrc[(size_t)row * add_ld + col];
                Cp[(size_t)row * ldc + col] = v;
            }
        }
    }
}

// ---------------------------------------------------------------------------
// Depthwise causal conv(4) + SiLU; softplus(dt); dA = exp(dt * -exp(A_log)).
// Bwd direction = tap reversal at original index. xs written bf16.
// ---------------------------------------------------------------------------
__global__ __launch_bounds__(256) void conv_dt_kernel(
    const float* __restrict__ zx,
    const float* __restrict__ cw0, const float* __restrict__ cw1,
    const float* __restrict__ cb0, const float* __restrict__ cb1,
    const float* __restrict__ dtbias0, const float* __restrict__ dtbias1,
    const float* __restrict__ Alog0, const float* __restrict__ Alog1,
    __hip_bfloat16* __restrict__ xs, float* __restrict__ Bcb, float* __restrict__ Ccb,
    float* __restrict__ dtb, float* __restrict__ dab)
{
    const int dir = blockIdx.y;
    const int row = blockIdx.x;          // b*L + l
    const int b = row >> 11;
    const int l = row & (L_SEQ - 1);

    const float* __restrict__ cw = dir ? cw1 : cw0;
    const float* __restrict__ cb = dir ? cb1 : cb0;
    const float* __restrict__ dtbias = dir ? dtbias1 : dtbias0;
    const float* __restrict__ Alog = dir ? Alog1 : Alog0;
    const float* __restrict__ zbase = zx + (size_t)dir * M_ROWS * DPROJ;
    const size_t orow = (size_t)(dir * M_ROWS + row);

    for (int c = threadIdx.x; c < CONVDIM; c += 256) {
        float acc = cb[c];
        const float w0 = cw[c * 4 + 0], w1 = cw[c * 4 + 1];
        const float w2 = cw[c * 4 + 2], w3 = cw[c * 4 + 3];
        if (dir == 0) {
#pragma unroll
            for (int k = 0; k < 4; ++k) {
                const int p = l - 3 + k;
                if (p >= 0) {
                    const float wv = (k == 0) ? w0 : (k == 1) ? w1 : (k == 2) ? w2 : w3;
                    acc += zbase[(size_t)(b * L_SEQ + p) * DPROJ + DINNER + c] * wv;
                }
            }
        } else {
#pragma unroll
            for (int k = 0; k < 4; ++k) {
                const int p = l + 3 - k;
                if (p < L_SEQ) {
                    const float wv = (k == 0) ? w0 : (k == 1) ? w1 : (k == 2) ? w2 : w3;
                    acc += zbase[(size_t)(b * L_SEQ + p) * DPROJ + DINNER + c] * wv;
                }
            }
        }
        const float s = acc / (1.f + expf(-acc));   // SiLU
        if (c < DINNER)            xs[orow * DINNER + c] = __float2bfloat16(s);
        else if (c < DINNER + NST) Bcb[orow * NST + (c - DINNER)] = s;
        else                       Ccb[orow * NST + (c - DINNER - NST)] = s;
    }

    if (threadIdx.x < NH) {
        const int h = threadIdx.x;
        const float v = zbase[(size_t)row * DPROJ + (DINNER + CONVDIM) + h] + dtbias[h];
        const float sp = (v > 20.f) ? v : log1pf(expf(v));
        const float a = -expf(Alog[h]);
        dtb[orow * NH + h] = sp;
        dab[orow * NH + h] = expf(sp * a);
    }
}

// ---------------------------------------------------------------------------
// Pass A: segment-local scan (zero init). Writes y_local+D*x to zx y-slice,
// inclusive decay cumprod betac[t], end state c -> stateC (bf16).
// Block = (dir, b, h, seg), 512 threads: p=tid>>3, n-slice 16 per thread.
// sB/sC swizzled [8][20] -> bank-conflict-free reads.
// ---------------------------------------------------------------------------
__global__ __launch_bounds__(512) void scan_seg_kernel(
    const __hip_bfloat16* __restrict__ xs, const float* __restrict__ Bcb,
    const float* __restrict__ Ccb, const float* __restrict__ dtb,
    const float* __restrict__ dab,
    const float* __restrict__ D0, const float* __restrict__ D1,
    float* __restrict__ zx, __hip_bfloat16* __restrict__ stateC,
    float* __restrict__ betac)
{
    const int dir = blockIdx.y;
    const int bx  = blockIdx.x;          // bh*NSEG + seg
    const int bh  = bx >> 3;
    const int seg = bx & 7;
    const int b = bh >> 5, h = bh & 31;
    const int tid = threadIdx.x;
    const int p = tid >> 3;
    const int g = tid & 7;
    const float Dv = (dir ? D1 : D0)[h];
    const int base_bh = (dir * 2 + b) * 32 + h;
    const int t0 = seg * SEGLEN;

    __shared__ float sx[2][64];
    __shared__ float sB[2][8][20];
    __shared__ float sC[2][8][20];
    __shared__ float sS[2][2];

    float hst[16];
#pragma unroll
    for (int i = 0; i < 16; ++i) hst[i] = 0.f;
    float beta = 1.f;

    const size_t dbase = (size_t)(dir * M_ROWS + b * L_SEQ);
    float* __restrict__ ybase = zx + (size_t)dir * M_ROWS * DPROJ + DINNER;

    {   // preload t0 into buf 0
        const int l = dir ? (L_SEQ - 1 - t0) : t0;
        const size_t r = dbase + l;
        if (tid < 64)        sx[0][tid] = __bfloat162float(xs[r * DINNER + h * 64 + tid]);
        else if (tid < 192)  { const int n = tid - 64;  sB[0][n >> 4][n & 15] = Bcb[r * NST + n]; }
        else if (tid < 320)  { const int n = tid - 192; sC[0][n >> 4][n & 15] = Ccb[r * NST + n]; }
        else if (tid == 320) sS[0][0] = dtb[r * NH + h];
        else if (tid == 321) sS[0][1] = dab[r * NH + h];
    }
    __syncthreads();

    for (int tt = 0; tt < SEGLEN; ++tt) {
        const int t = t0 + tt;
        const int cur = tt & 1, nxt = cur ^ 1;

        float pv = 0.f;
        const bool havenext = (tt + 1 < SEGLEN);
        if (havenext) {
            const int tn = t + 1;
            const int ln = dir ? (L_SEQ - 1 - tn) : tn;
            const size_t r = dbase + ln;
            if (tid < 64)        pv = __bfloat162float(xs[r * DINNER + h * 64 + tid]);
            else if (tid < 192)  pv = Bcb[r * NST + (tid - 64)];
            else if (tid < 320)  pv = Ccb[r * NST + (tid - 192)];
            else if (tid == 320) pv = dtb[r * NH + h];
            else if (tid == 321) pv = dab[r * NH + h];
        }

        const float dtv = sS[cur][0];
        const float dav = sS[cur][1];
        const float xv  = sx[cur][p];
        const float sxv = dtv * xv;
        const float* __restrict__ Bp = sB[cur][g];
        const float* __restrict__ Cp = sC[cur][g];
        float acc0 = 0.f, acc1 = 0.f;
#pragma unroll
        for (int j = 0; j < 16; j += 2) {
            hst[j]     = fmaf(hst[j],     dav, sxv * Bp[j]);
            hst[j + 1] = fmaf(hst[j + 1], dav, sxv * Bp[j + 1]);
            acc0 = fmaf(hst[j],     Cp[j],     acc0);
            acc1 = fmaf(hst[j + 1], Cp[j + 1], acc1);
        }
        float acc = acc0 + acc1;
        acc += __shfl_xor(acc, 1);
        acc += __shfl_xor(acc, 2);
        acc += __shfl_xor(acc, 4);

        beta *= dav;
        if (tid == 0) betac[(size_t)base_bh * L_SEQ + t] = beta;
        if (g == 0) {
            const int l = dir ? (L_SEQ - 1 - t) : t;
            ybase[(size_t)(b * L_SEQ + l) * DPROJ + h * 64 + p] = acc + Dv * xv;
        }

        if (havenext) {
            if (tid < 64)        sx[nxt][tid] = pv;
            else if (tid < 192)  { const int n = tid - 64;  sB[nxt][n >> 4][n & 15] = pv; }
            else if (tid < 320)  { const int n = tid - 192; sC[nxt][n >> 4][n & 15] = pv; }
            else if (tid == 320) sS[nxt][0] = pv;
            else if (tid == 321) sS[nxt][1] = pv;
        }
        __syncthreads();
    }

    // store segment end-state (thread tid owns contiguous [tid*16, tid*16+16))
    const size_t soff = ((size_t)(base_bh * NSEG + seg)) * 8192 + (size_t)tid * 16;
#pragma unroll
    for (int j = 0; j < 16; ++j)
        stateC[soff + j] = __float2bfloat16(hst[j]);
}

// ---------------------------------------------------------------------------
// Pass B: sequential combine over segments (in place: stateC[s] becomes h_in
// for segment s). Block = (dir, b, h), thread owns 16 contiguous state elems.
// ---------------------------------------------------------------------------
__global__ __launch_bounds__(512) void combine_kernel(
    __hip_bfloat16* __restrict__ stateC, const float* __restrict__ betac)
{
    const int dir = blockIdx.y;
    const int bh  = blockIdx.x;
    const int base_bh = (dir * 2 + (bh >> 5)) * 32 + (bh & 31);
    const int tid = threadIdx.x;

    float hrun[16];
#pragma unroll
    for (int j = 0; j < 16; ++j) hrun[j] = 0.f;

    for (int s = 0; s < NSEG; ++s) {
        const size_t off = ((size_t)(base_bh * NSEG + s)) * 8192 + (size_t)tid * 16;
        float c[16];
#pragma unroll
        for (int j = 0; j < 16; ++j) c[j] = __bfloat162float(stateC[off + j]);
#pragma unroll
        for (int j = 0; j < 16; ++j) stateC[off + j] = __float2bfloat16(hrun[j]);
        const float alpha = betac[(size_t)base_bh * L_SEQ + s * SEGLEN + (SEGLEN - 1)];
#pragma unroll
        for (int j = 0; j < 16; ++j) hrun[j] = fmaf(alpha, hrun[j], c[j]);
    }
}

// ---------------------------------------------------------------------------
// Pass C: y_t += betac[t] * (C_t . h_in[p,:]). Block = (dir,b,h,seg>0).
// ---------------------------------------------------------------------------
__global__ __launch_bounds__(512) void correct_kernel(
    const float* __restrict__ Ccb, const float* __restrict__ betac,
    const __hip_bfloat16* __restrict__ stateC, float* __restrict__ zx)
{
    const int dir = blockIdx.y;
    const int bx  = blockIdx.x;
    const int bh  = bx >> 3;
    const int seg = bx & 7;
    if (seg == 0) return;                  // h_in == 0
    const int b = bh >> 5, h = bh & 31;
    const int tid = threadIdx.x;
    const int p = tid >> 3;
    const int g = tid & 7;
    const int base_bh = (dir * 2 + b) * 32 + h;
    const int t0 = seg * SEGLEN;

    float hin[16];
    {
        const size_t off = ((size_t)(base_bh * NSEG + seg)) * 8192 + (size_t)tid * 16;
#pragma unroll
        for (int j = 0; j < 16; ++j) hin[j] = __bfloat162float(stateC[off + j]);
    }

    __shared__ float sC[2][8][20];
    __shared__ float sbeta[2];

    const size_t dbase = (size_t)(dir * M_ROWS + b * L_SEQ);
    float* __restrict__ ybase = zx + (size_t)dir * M_ROWS * DPROJ + DINNER;

    {   // preload t0
        const int l = dir ? (L_SEQ - 1 - t0) : t0;
        const size_t r = dbase + l;
        if (tid < 128)       sC[0][tid >> 4][tid & 15] = Ccb[r * NST + tid];
        else if (tid == 128) sbeta[0] = betac[(size_t)base_bh * L_SEQ + t0];
    }
    __syncthreads();

    for (int tt = 0; tt < SEGLEN; ++tt) {
        const int t = t0 + tt;
        const int cur = tt & 1, nxt = cur ^ 1;

        float pv = 0.f;
        const bool havenext = (tt + 1 < SEGLEN);
        if (havenext) {
            const int tn = t + 1;
            const int ln = dir ? (L_SEQ - 1 - tn) : tn;
            const size_t r = dbase + ln;
            if (tid < 128)       pv = Ccb[r * NST + tid];
            else if (tid == 128) pv = betac[(size_t)base_bh * L_SEQ + tn];
        }

        const float* __restrict__ Cp = sC[cur][g];
        float acc0 = 0.f, acc1 = 0.f;
#pragma unroll
        for (int j = 0; j < 16; j += 2) {
            acc0 = fmaf(hin[j],     Cp[j],     acc0);
            acc1 = fmaf(hin[j + 1], Cp[j + 1], acc1);
        }
        float acc = acc0 + acc1;
        acc += __shfl_xor(acc, 1);
        acc += __shfl_xor(acc, 2);
        acc += __shfl_xor(acc, 4);
        if (g == 0) {
            const int l = dir ? (L_SEQ - 1 - t) : t;
            float* yp = &ybase[(size_t)(b * L_SEQ + l) * DPROJ + h * 64 + p];
            *yp += sbeta[cur] * acc;
        }

        if (havenext) {
            if (tid < 128)       sC[nxt][tid >> 4][tid & 15] = pv;
            else if (tid == 128) sbeta[nxt] = pv;
        }
        __syncthreads();
    }
}

// ---------------------------------------------------------------------------
// y = y * silu(z); RMSNorm(2048) * norm_w, in place on y slice of zx.
// ---------------------------------------------------------------------------
__global__ __launch_bounds__(256) void gatenorm_kernel(
    float* __restrict__ zx,
    const float* __restrict__ nw0, const float* __restrict__ nw1)
{
    const int dir = blockIdx.y;
    const int row = blockIdx.x;
    const float* __restrict__ nw = dir ? nw1 : nw0;
    float* __restrict__ rowp = zx + (size_t)dir * M_ROWS * DPROJ + (size_t)row * DPROJ;
    const int tid = threadIdx.x;

    float gv[8];
    float ss = 0.f;
#pragma unroll
    for (int i = 0; i < 8; ++i) {
        const int c = i * 256 + tid;
        const float yv = rowp[DINNER + c];
        const float zv = rowp[c];
        const float gg = yv * (zv / (1.f + expf(-zv)));
        gv[i] = gg;
        ss = fmaf(gg, gg, ss);
    }
#pragma unroll
    for (int off = 1; off < 64; off <<= 1) ss += __shfl_xor(ss, off);
    __shared__ float red[4];
    if ((tid & 63) == 0) red[tid >> 6] = ss;
    __syncthreads();
    const float total = red[0] + red[1] + red[2] + red[3];
    const float rs = rsqrtf(total * (1.f / (float)DINNER) + 1e-5f);
#pragma unroll
    for (int i = 0; i < 8; ++i) {
        const int c = i * 256 + tid;
        rowp[DINNER + c] = gv[i] * rs * nw[c];
    }
}

// ---------------------------------------------------------------------------
extern "C" void kernel_launch(void* const* d_in, const int* in_sizes, int n_in,
                              void* d_out, int out_size, void* d_ws, size_t ws_size,
                              hipStream_t stream)
{
    (void)in_sizes; (void)n_in; (void)out_size; (void)ws_size;
    const float* x        = (const float*)d_in[0];
    const float* f_in_w   = (const float*)d_in[1];
    const float* f_conv_w = (const float*)d_in[2];
    const float* f_conv_b = (const float*)d_in[3];
    const float* f_dtbias = (const float*)d_in[4];
    const float* f_Alog   = (const float*)d_in[5];
    const float* f_D      = (const float*)d_in[6];
    const float* f_nw     = (const float*)d_in[7];
    const float* f_out_w  = (const float*)d_in[8];
    const float* b_in_w   = (const float*)d_in[9];
    const float* b_conv_w = (const float*)d_in[10];
    const float* b_conv_b = (const float*)d_in[11];
    const float* b_dtbias = (const float*)d_in[12];
    const float* b_Alog   = (const float*)d_in[13];
    const float* b_D      = (const float*)d_in[14];
    const float* b_nw     = (const float*)d_in[15];
    const float* b_out_w  = (const float*)d_in[16];

    // Workspace (205.5 MB): zx 143.7 | xs bf16 33.6 | B,C f32 8.4 | dt,dA 2.1
    //                       | stateC bf16 16.8 | betac f32 1.0
    float* ws  = (float*)d_ws;
    float* zx  = ws;
    __hip_bfloat16* xs = (__hip_bfloat16*)(zx + (size_t)2 * M_ROWS * DPROJ);
    float* Bcb = (float*)(xs + (size_t)2 * M_ROWS * DINNER);
    float* Ccb = Bcb + (size_t)2 * M_ROWS * NST;
    float* dtb = Ccb + (size_t)2 * M_ROWS * NST;
    float* dab = dtb + (size_t)2 * M_ROWS * NH;
    __hip_bfloat16* stateC = (__hip_bfloat16*)(dab + (size_t)2 * M_ROWS * NH);
    float* betac = (float*)(stateC + (size_t)128 * NSEG * 8192);

    // 1) in_proj: zx[dir] = x @ in_w[dir]^T   (M=4096, N=4384, K=512)
    gemm_f32<<<dim3(69, 64, 2), 256, 0, stream>>>(
        x, x, 512, f_in_w, b_in_w,
        zx, (long long)M_ROWS * DPROJ, DPROJ,
        nullptr, 0, M_ROWS, DPROJ, 512);

    // 2) conv + SiLU + dt/dA
    conv_dt_kernel<<<dim3(M_ROWS, 2), 256, 0, stream>>>(
        zx, f_conv_w, b_conv_w, f_conv_b, b_conv_b,
        f_dtbias, b_dtbias, f_Alog, b_Alog,
        xs, Bcb, Ccb, dtb, dab);

    // 3a) segment-local scans (+ D-skip into y slice of zx)
    scan_seg_kernel<<<dim3(64 * NSEG, 2), 512, 0, stream>>>(
        xs, Bcb, Ccb, dtb, dab, f_D, b_D, zx, stateC, betac);

    // 3b) combine segment states
    combine_kernel<<<dim3(64, 2), 512, 0, stream>>>(stateC, betac);

    // 3c) inter-segment correction
    correct_kernel<<<dim3(64 * NSEG, 2), 512, 0, stream>>>(Ccb, betac, stateC, zx);

    // 4) gate + RMSNorm in place on y slice
    gatenorm_kernel<<<dim3(M_ROWS, 2), 256, 0, stream>>>(zx, f_nw, b_nw);

    // 5) out_proj + residual + concat
    gemm_f32<<<dim3(8, 64, 2), 256, 0, stream>>>(
        zx + DINNER, zx + (size_t)M_ROWS * DPROJ + DINNER, DPROJ,
        f_out_w, b_out_w,
        (float*)d_out, 512, 1024,
        x, 512, M_ROWS, 512, DINNER);
}

// Round 4
// 1080.514 us; speedup vs baseline: 2.6463x; 1.4706x over previous
//
#include <hip/hip_runtime.h>
#include <hip/hip_bf16.h>
#include <math.h>

#define L_SEQ   2048
#define M_ROWS  4096            // B*L
#define DPROJ   4384
#define DPROJP  4480            // padded to 35*128 for MFMA GEMM
#define DINNER  2048
#define CONVDIM 2304
#define NST     128
#define NH      32
#define SEGLEN  256
#define NSEG    8

typedef __attribute__((ext_vector_type(8))) short short8;
typedef __attribute__((ext_vector_type(4))) float f32x4;

union bf8u { short8 v; __hip_bfloat16 e[8]; };

// ---------------------------------------------------------------------------
// f32 -> bf16 conversion pre-passes
// ---------------------------------------------------------------------------
__global__ __launch_bounds__(256) void cvt_x_kernel(
    const float* __restrict__ x, __hip_bfloat16* __restrict__ xbf)
{
    const int i = (blockIdx.x * 256 + threadIdx.x) * 4;   // over 4096*512
    const float4 v = *(const float4*)(x + i);
    xbf[i + 0] = __float2bfloat16(v.x);
    xbf[i + 1] = __float2bfloat16(v.y);
    xbf[i + 2] = __float2bfloat16(v.z);
    xbf[i + 3] = __float2bfloat16(v.w);
}

__global__ __launch_bounds__(256) void cvt_win_kernel(
    const float* __restrict__ w0, const float* __restrict__ w1,
    __hip_bfloat16* __restrict__ dst)
{
    const int dir = blockIdx.y;
    const float* __restrict__ w = dir ? w1 : w0;
    __hip_bfloat16* __restrict__ d = dst + (size_t)dir * DPROJP * 512;
    const int i = (blockIdx.x * 256 + threadIdx.x) * 4;   // over 4480*512
    const int row = i >> 9;
    if (row < DPROJ) {
        const float4 v = *(const float4*)(w + i);
        d[i + 0] = __float2bfloat16(v.x);
        d[i + 1] = __float2bfloat16(v.y);
        d[i + 2] = __float2bfloat16(v.z);
        d[i + 3] = __float2bfloat16(v.w);
    } else {
        d[i + 0] = __float2bfloat16(0.f); d[i + 1] = __float2bfloat16(0.f);
        d[i + 2] = __float2bfloat16(0.f); d[i + 3] = __float2bfloat16(0.f);
    }
}

__global__ __launch_bounds__(256) void cvt_wout_kernel(
    const float* __restrict__ w0, const float* __restrict__ w1,
    __hip_bfloat16* __restrict__ dst)
{
    const int dir = blockIdx.y;
    const float* __restrict__ w = dir ? w1 : w0;
    __hip_bfloat16* __restrict__ d = dst + (size_t)dir * 512 * DINNER;
    const int i = (blockIdx.x * 256 + threadIdx.x) * 4;   // over 512*2048
    const float4 v = *(const float4*)(w + i);
    d[i + 0] = __float2bfloat16(v.x);
    d[i + 1] = __float2bfloat16(v.y);
    d[i + 2] = __float2bfloat16(v.z);
    d[i + 3] = __float2bfloat16(v.w);
}

// ---------------------------------------------------------------------------
// MFMA bf16 GEMM: C[M][N] = A[M][K] @ B[N][K]^T (+ optional f32 addsrc).
// 128x128 tile, BK=64, 256 threads (4 waves, each 64x64 = 4x4 frags of
// 16x16x32). LDS XOR-swizzled ((slot^(row&7))*16B) for conflict-free
// ds_read_b128. A source: bf16 [M][K] (AF32=false) or f32 strided (AF32=true,
// converted during staging).
// ---------------------------------------------------------------------------
template<bool AF32>
__global__ __launch_bounds__(256) void gemm_mfma(
    const __hip_bfloat16* __restrict__ Abf,                 // AF32=false
    const float* __restrict__ Af0, const float* __restrict__ Af1, int lda_f,
    const __hip_bfloat16* __restrict__ Bw, long long b_dir_off,
    float* __restrict__ C, long long c_dir_off, int ldc,
    const float* __restrict__ addsrc, int add_ld,
    int K)
{
    const int dir = blockIdx.z;
    const int m0 = blockIdx.y * 128;
    const int n0 = blockIdx.x * 128;
    const __hip_bfloat16* __restrict__ B = Bw + (size_t)dir * b_dir_off;
    const float* __restrict__ Af = dir ? Af1 : Af0;
    float* __restrict__ Cp = C + (size_t)dir * c_dir_off;

    __shared__ __hip_bfloat16 Asl[128 * 64];
    __shared__ __hip_bfloat16 Bsl[128 * 64];

    const int tid  = threadIdx.x;
    const int lane = tid & 63;
    const int wid  = tid >> 6;
    const int wr   = (wid >> 1) << 6;
    const int wc   = (wid & 1) << 6;
    const int l15  = lane & 15;
    const int l4   = lane >> 4;

    f32x4 acc[4][4];
#pragma unroll
    for (int m = 0; m < 4; ++m)
#pragma unroll
        for (int n = 0; n < 4; ++n) acc[m][n] = (f32x4)0.f;

    for (int k0 = 0; k0 < K; k0 += 64) {
        __syncthreads();   // previous compute done before overwriting LDS
#pragma unroll
        for (int i = 0; i < 4; ++i) {
            const int c    = tid + (i << 8);       // 0..1023
            const int row  = c >> 3;               // 0..127
            const int slot = c & 7;                // 16B slot in 128B row
            const int dst  = (row << 7) + ((slot ^ (row & 7)) << 4);
            if (AF32) {
                const float* s = Af + (size_t)(m0 + row) * lda_f + k0 + (slot << 3);
                const float4 lo = *(const float4*)(s);
                const float4 hi = *(const float4*)(s + 4);
                bf8u u;
                u.e[0] = __float2bfloat16(lo.x); u.e[1] = __float2bfloat16(lo.y);
                u.e[2] = __float2bfloat16(lo.z); u.e[3] = __float2bfloat16(lo.w);
                u.e[4] = __float2bfloat16(hi.x); u.e[5] = __float2bfloat16(hi.y);
                u.e[6] = __float2bfloat16(hi.z); u.e[7] = __float2bfloat16(hi.w);
                *(short8*)((char*)Asl + dst) = u.v;
            } else {
                *(short8*)((char*)Asl + dst) =
                    *(const short8*)(Abf + (size_t)(m0 + row) * K + k0 + (slot << 3));
            }
            *(short8*)((char*)Bsl + dst) =
                *(const short8*)(B + (size_t)(n0 + row) * K + k0 + (slot << 3));
        }
        __syncthreads();

#pragma unroll
        for (int kh = 0; kh < 2; ++kh) {
            const int ks = (kh << 2) + l4;         // 16B k-slot index 0..7
            short8 a[4], b[4];
#pragma unroll
            for (int m = 0; m < 4; ++m) {
                const int R = wr + (m << 4) + l15;
                a[m] = *(const short8*)((const char*)Asl + (R << 7) + ((ks ^ (R & 7)) << 4));
            }
#pragma unroll
            for (int n = 0; n < 4; ++n) {
                const int R = wc + (n << 4) + l15;
                b[n] = *(const short8*)((const char*)Bsl + (R << 7) + ((ks ^ (R & 7)) << 4));
            }
#pragma unroll
            for (int m = 0; m < 4; ++m)
#pragma unroll
                for (int n = 0; n < 4; ++n)
                    acc[m][n] = __builtin_amdgcn_mfma_f32_16x16x32_bf16(
                        a[m], b[n], acc[m][n], 0, 0, 0);
        }
    }

#pragma unroll
    for (int m = 0; m < 4; ++m) {
        const int row0 = m0 + wr + (m << 4) + (l4 << 2);
#pragma unroll
        for (int n = 0; n < 4; ++n) {
            const int col = n0 + wc + (n << 4) + l15;
#pragma unroll
            for (int r = 0; r < 4; ++r) {
                float v = acc[m][n][r];
                if (addsrc) v += addsrc[(size_t)(row0 + r) * add_ld + col];
                Cp[(size_t)(row0 + r) * ldc + col] = v;
            }
        }
    }
}

// ---------------------------------------------------------------------------
// Depthwise causal conv(4) + SiLU on xBC cols of zx; dt recomputed EXACTLY in
// f32 from x @ in_w (exp-amplified path kept full precision); softplus;
// dA = exp(dt * -exp(A_log)). Bwd = tap reversal at original index.
// ---------------------------------------------------------------------------
__global__ __launch_bounds__(256) void conv_dt_kernel(
    const float* __restrict__ zx, const float* __restrict__ x,
    const float* __restrict__ inw0, const float* __restrict__ inw1,
    const float* __restrict__ cw0, const float* __restrict__ cw1,
    const float* __restrict__ cb0, const float* __restrict__ cb1,
    const float* __restrict__ dtbias0, const float* __restrict__ dtbias1,
    const float* __restrict__ Alog0, const float* __restrict__ Alog1,
    __hip_bfloat16* __restrict__ xs, float* __restrict__ Bcb, float* __restrict__ Ccb,
    float* __restrict__ dtb, float* __restrict__ dab)
{
    const int dir = blockIdx.y;
    const int row = blockIdx.x;          // b*L + l
    const int b = row >> 11;
    const int l = row & (L_SEQ - 1);

    const float* __restrict__ cw = dir ? cw1 : cw0;
    const float* __restrict__ cb = dir ? cb1 : cb0;
    const float* __restrict__ zbase = zx + (size_t)dir * M_ROWS * DPROJP;
    const size_t orow = (size_t)(dir * M_ROWS + row);

    for (int c = threadIdx.x; c < CONVDIM; c += 256) {
        float acc = cb[c];
        const float w0 = cw[c * 4 + 0], w1 = cw[c * 4 + 1];
        const float w2 = cw[c * 4 + 2], w3 = cw[c * 4 + 3];
        if (dir == 0) {
#pragma unroll
            for (int k = 0; k < 4; ++k) {
                const int p = l - 3 + k;
                if (p >= 0) {
                    const float wv = (k == 0) ? w0 : (k == 1) ? w1 : (k == 2) ? w2 : w3;
                    acc += zbase[(size_t)(b * L_SEQ + p) * DPROJP + DINNER + c] * wv;
                }
            }
        } else {
#pragma unroll
            for (int k = 0; k < 4; ++k) {
                const int p = l + 3 - k;
                if (p < L_SEQ) {
                    const float wv = (k == 0) ? w0 : (k == 1) ? w1 : (k == 2) ? w2 : w3;
                    acc += zbase[(size_t)(b * L_SEQ + p) * DPROJP + DINNER + c] * wv;
                }
            }
        }
        const float s = acc / (1.f + expf(-acc));   // SiLU
        if (c < DINNER)            xs[orow * DINNER + c] = __float2bfloat16(s);
        else if (c < DINNER + NST) Bcb[orow * NST + (c - DINNER)] = s;
        else                       Ccb[orow * NST + (c - DINNER - NST)] = s;
    }

    // exact f32 dt: 8 threads per head
    {
        const int h = threadIdx.x >> 3;
        const int part = threadIdx.x & 7;
        const float* __restrict__ xr = x + (size_t)row * 512 + part * 64;
        const float* __restrict__ wr_ = (dir ? inw1 : inw0)
            + (size_t)(DINNER + CONVDIM + h) * 512 + part * 64;
        float s = 0.f;
#pragma unroll
        for (int k = 0; k < 64; ++k) s = fmaf(xr[k], wr_[k], s);
        s += __shfl_xor(s, 1);
        s += __shfl_xor(s, 2);
        s += __shfl_xor(s, 4);
        if (part == 0) {
            const float v = s + (dir ? dtbias1 : dtbias0)[h];
            const float sp = (v > 20.f) ? v : log1pf(expf(v));
            const float a = -expf((dir ? Alog1 : Alog0)[h]);
            dtb[orow * NH + h] = sp;
            dab[orow * NH + h] = expf(sp * a);
        }
    }
}

// ---------------------------------------------------------------------------
// Pass A: segment-local scan (zero init). Writes y_local+D*x to zx y-slice,
// inclusive decay cumprod betac[t], end state -> stateC (bf16).
// ---------------------------------------------------------------------------
__global__ __launch_bounds__(512) void scan_seg_kernel(
    const __hip_bfloat16* __restrict__ xs, const float* __restrict__ Bcb,
    const float* __restrict__ Ccb, const float* __restrict__ dtb,
    const float* __restrict__ dab,
    const float* __restrict__ D0, const float* __restrict__ D1,
    float* __restrict__ zx, __hip_bfloat16* __restrict__ stateC,
    float* __restrict__ betac)
{
    const int dir = blockIdx.y;
    const int bx  = blockIdx.x;          // bh*NSEG + seg
    const int bh  = bx >> 3;
    const int seg = bx & 7;
    const int b = bh >> 5, h = bh & 31;
    const int tid = threadIdx.x;
    const int p = tid >> 3;
    const int g = tid & 7;
    const float Dv = (dir ? D1 : D0)[h];
    const int base_bh = (dir * 2 + b) * 32 + h;
    const int t0 = seg * SEGLEN;

    __shared__ float sx[2][64];
    __shared__ float sB[2][8][20];
    __shared__ float sC[2][8][20];
    __shared__ float sS[2][2];

    float hst[16];
#pragma unroll
    for (int i = 0; i < 16; ++i) hst[i] = 0.f;
    float beta = 1.f;

    const size_t dbase = (size_t)(dir * M_ROWS + b * L_SEQ);
    float* __restrict__ ybase = zx + (size_t)dir * M_ROWS * DPROJP + DINNER;

    {
        const int l = dir ? (L_SEQ - 1 - t0) : t0;
        const size_t r = dbase + l;
        if (tid < 64)        sx[0][tid] = __bfloat162float(xs[r * DINNER + h * 64 + tid]);
        else if (tid < 192)  { const int n = tid - 64;  sB[0][n >> 4][n & 15] = Bcb[r * NST + n]; }
        else if (tid < 320)  { const int n = tid - 192; sC[0][n >> 4][n & 15] = Ccb[r * NST + n]; }
        else if (tid == 320) sS[0][0] = dtb[r * NH + h];
        else if (tid == 321) sS[0][1] = dab[r * NH + h];
    }
    __syncthreads();

    for (int tt = 0; tt < SEGLEN; ++tt) {
        const int t = t0 + tt;
        const int cur = tt & 1, nxt = cur ^ 1;

        float pv = 0.f;
        const bool havenext = (tt + 1 < SEGLEN);
        if (havenext) {
            const int tn = t + 1;
            const int ln = dir ? (L_SEQ - 1 - tn) : tn;
            const size_t r = dbase + ln;
            if (tid < 64)        pv = __bfloat162float(xs[r * DINNER + h * 64 + tid]);
            else if (tid < 192)  pv = Bcb[r * NST + (tid - 64)];
            else if (tid < 320)  pv = Ccb[r * NST + (tid - 192)];
            else if (tid == 320) pv = dtb[r * NH + h];
            else if (tid == 321) pv = dab[r * NH + h];
        }

        const float dtv = sS[cur][0];
        const float dav = sS[cur][1];
        const float xv  = sx[cur][p];
        const float sxv = dtv * xv;
        const float* __restrict__ Bp = sB[cur][g];
        const float* __restrict__ Cp = sC[cur][g];
        float acc0 = 0.f, acc1 = 0.f;
#pragma unroll
        for (int j = 0; j < 16; j += 2) {
            hst[j]     = fmaf(hst[j],     dav, sxv * Bp[j]);
            hst[j + 1] = fmaf(hst[j + 1], dav, sxv * Bp[j + 1]);
            acc0 = fmaf(hst[j],     Cp[j],     acc0);
            acc1 = fmaf(hst[j + 1], Cp[j + 1], acc1);
        }
        float acc = acc0 + acc1;
        acc += __shfl_xor(acc, 1);
        acc += __shfl_xor(acc, 2);
        acc += __shfl_xor(acc, 4);

        beta *= dav;
        if (tid == 0) betac[(size_t)base_bh * L_SEQ + t] = beta;
        if (g == 0) {
            const int l = dir ? (L_SEQ - 1 - t) : t;
            ybase[(size_t)(b * L_SEQ + l) * DPROJP + h * 64 + p] = acc + Dv * xv;
        }

        if (havenext) {
            if (tid < 64)        sx[nxt][tid] = pv;
            else if (tid < 192)  { const int n = tid - 64;  sB[nxt][n >> 4][n & 15] = pv; }
            else if (tid < 320)  { const int n = tid - 192; sC[nxt][n >> 4][n & 15] = pv; }
            else if (tid == 320) sS[nxt][0] = pv;
            else if (tid == 321) sS[nxt][1] = pv;
        }
        __syncthreads();
    }

    const size_t soff = ((size_t)(base_bh * NSEG + seg)) * 8192 + (size_t)tid * 16;
#pragma unroll
    for (int j = 0; j < 16; ++j)
        stateC[soff + j] = __float2bfloat16(hst[j]);
}

// ---------------------------------------------------------------------------
// Pass B: sequential combine over segments (in place).
// ---------------------------------------------------------------------------
__global__ __launch_bounds__(512) void combine_kernel(
    __hip_bfloat16* __restrict__ stateC, const float* __restrict__ betac)
{
    const int dir = blockIdx.y;
    const int bh  = blockIdx.x;
    const int base_bh = (dir * 2 + (bh >> 5)) * 32 + (bh & 31);
    const int tid = threadIdx.x;

    float hrun[16];
#pragma unroll
    for (int j = 0; j < 16; ++j) hrun[j] = 0.f;

    for (int s = 0; s < NSEG; ++s) {
        const size_t off = ((size_t)(base_bh * NSEG + s)) * 8192 + (size_t)tid * 16;
        float c[16];
#pragma unroll
        for (int j = 0; j < 16; ++j) c[j] = __bfloat162float(stateC[off + j]);
#pragma unroll
        for (int j = 0; j < 16; ++j) stateC[off + j] = __float2bfloat16(hrun[j]);
        const float alpha = betac[(size_t)base_bh * L_SEQ + s * SEGLEN + (SEGLEN - 1)];
#pragma unroll
        for (int j = 0; j < 16; ++j) hrun[j] = fmaf(alpha, hrun[j], c[j]);
    }
}

// ---------------------------------------------------------------------------
// Pass C: y_t += betac[t] * (C_t . h_in[p,:]).
// ---------------------------------------------------------------------------
__global__ __launch_bounds__(512) void correct_kernel(
    const float* __restrict__ Ccb, const float* __restrict__ betac,
    const __hip_bfloat16* __restrict__ stateC, float* __restrict__ zx)
{
    const int dir = blockIdx.y;
    const int bx  = blockIdx.x;
    const int bh  = bx >> 3;
    const int seg = bx & 7;
    if (seg == 0) return;
    const int b = bh >> 5, h = bh & 31;
    const int tid = threadIdx.x;
    const int p = tid >> 3;
    const int g = tid & 7;
    const int base_bh = (dir * 2 + b) * 32 + h;
    const int t0 = seg * SEGLEN;

    float hin[16];
    {
        const size_t off = ((size_t)(base_bh * NSEG + seg)) * 8192 + (size_t)tid * 16;
#pragma unroll
        for (int j = 0; j < 16; ++j) hin[j] = __bfloat162float(stateC[off + j]);
    }

    __shared__ float sC[2][8][20];
    __shared__ float sbeta[2];

    const size_t dbase = (size_t)(dir * M_ROWS + b * L_SEQ);
    float* __restrict__ ybase = zx + (size_t)dir * M_ROWS * DPROJP + DINNER;

    {
        const int l = dir ? (L_SEQ - 1 - t0) : t0;
        const size_t r = dbase + l;
        if (tid < 128)       sC[0][tid >> 4][tid & 15] = Ccb[r * NST + tid];
        else if (tid == 128) sbeta[0] = betac[(size_t)base_bh * L_SEQ + t0];
    }
    __syncthreads();

    for (int tt = 0; tt < SEGLEN; ++tt) {
        const int t = t0 + tt;
        const int cur = tt & 1, nxt = cur ^ 1;

        float pv = 0.f;
        const bool havenext = (tt + 1 < SEGLEN);
        if (havenext) {
            const int tn = t + 1;
            const int ln = dir ? (L_SEQ - 1 - tn) : tn;
            const size_t r = dbase + ln;
            if (tid < 128)       pv = Ccb[r * NST + tid];
            else if (tid == 128) pv = betac[(size_t)base_bh * L_SEQ + tn];
        }

        const float* __restrict__ Cp = sC[cur][g];
        float acc0 = 0.f, acc1 = 0.f;
#pragma unroll
        for (int j = 0; j < 16; j += 2) {
            acc0 = fmaf(hin[j],     Cp[j],     acc0);
            acc1 = fmaf(hin[j + 1], Cp[j + 1], acc1);
        }
        float acc = acc0 + acc1;
        acc += __shfl_xor(acc, 1);
        acc += __shfl_xor(acc, 2);
        acc += __shfl_xor(acc, 4);
        if (g == 0) {
            const int l = dir ? (L_SEQ - 1 - t) : t;
            ybase[(size_t)(b * L_SEQ + l) * DPROJP + h * 64 + p] += sbeta[cur] * acc;
        }

        if (havenext) {
            if (tid < 128)       sC[nxt][tid >> 4][tid & 15] = pv;
            else if (tid == 128) sbeta[nxt] = pv;
        }
        __syncthreads();
    }
}

// ---------------------------------------------------------------------------
// y = y * silu(z); RMSNorm(2048) * norm_w, in place on y slice of zx.
// ---------------------------------------------------------------------------
__global__ __launch_bounds__(256) void gatenorm_kernel(
    float* __restrict__ zx,
    const float* __restrict__ nw0, const float* __restrict__ nw1)
{
    const int dir = blockIdx.y;
    const int row = blockIdx.x;
    const float* __restrict__ nw = dir ? nw1 : nw0;
    float* __restrict__ rowp = zx + (size_t)dir * M_ROWS * DPROJP + (size_t)row * DPROJP;
    const int tid = threadIdx.x;

    float gv[8];
    float ss = 0.f;
#pragma unroll
    for (int i = 0; i < 8; ++i) {
        const int c = i * 256 + tid;
        const float yv = rowp[DINNER + c];
        const float zv = rowp[c];
        const float gg = yv * (zv / (1.f + expf(-zv)));
        gv[i] = gg;
        ss = fmaf(gg, gg, ss);
    }
#pragma unroll
    for (int off = 1; off < 64; off <<= 1) ss += __shfl_xor(ss, off);
    __shared__ float red[4];
    if ((tid & 63) == 0) red[tid >> 6] = ss;
    __syncthreads();
    const float total = red[0] + red[1] + red[2] + red[3];
    const float rs = rsqrtf(total * (1.f / (float)DINNER) + 1e-5f);
#pragma unroll
    for (int i = 0; i < 8; ++i) {
        const int c = i * 256 + tid;
        rowp[DINNER + c] = gv[i] * rs * nw[c];
    }
}

// ---------------------------------------------------------------------------
extern "C" void kernel_launch(void* const* d_in, const int* in_sizes, int n_in,
                              void* d_out, int out_size, void* d_ws, size_t ws_size,
                              hipStream_t stream)
{
    (void)in_sizes; (void)n_in; (void)out_size; (void)ws_size;
    const float* x        = (const float*)d_in[0];
    const float* f_in_w   = (const float*)d_in[1];
    const float* f_conv_w = (const float*)d_in[2];
    const float* f_conv_b = (const float*)d_in[3];
    const float* f_dtbias = (const float*)d_in[4];
    const float* f_Alog   = (const float*)d_in[5];
    const float* f_D      = (const float*)d_in[6];
    const float* f_nw     = (const float*)d_in[7];
    const float* f_out_w  = (const float*)d_in[8];
    const float* b_in_w   = (const float*)d_in[9];
    const float* b_conv_w = (const float*)d_in[10];
    const float* b_conv_b = (const float*)d_in[11];
    const float* b_dtbias = (const float*)d_in[12];
    const float* b_Alog   = (const float*)d_in[13];
    const float* b_D      = (const float*)d_in[14];
    const float* b_nw     = (const float*)d_in[15];
    const float* b_out_w  = (const float*)d_in[16];

    // Workspace (~226 MB): zx(padded) 146.8 | xs bf16 33.6 | B,C 8.4 | dt,dA 2.1
    //   | stateC 16.8 | betac 1.05 | x_bf 4.2 | w_in_bf 9.2 | w_out_bf 4.2
    float* ws  = (float*)d_ws;
    float* zx  = ws;
    __hip_bfloat16* xs = (__hip_bfloat16*)(zx + (size_t)2 * M_ROWS * DPROJP);
    float* Bcb = (float*)(xs + (size_t)2 * M_ROWS * DINNER);
    float* Ccb = Bcb + (size_t)2 * M_ROWS * NST;
    float* dtb = Ccb + (size_t)2 * M_ROWS * NST;
    float* dab = dtb + (size_t)2 * M_ROWS * NH;
    __hip_bfloat16* stateC = (__hip_bfloat16*)(dab + (size_t)2 * M_ROWS * NH);
    float* betac = (float*)(stateC + (size_t)128 * NSEG * 8192);
    __hip_bfloat16* x_bf    = (__hip_bfloat16*)(betac + (size_t)128 * L_SEQ);
    __hip_bfloat16* w_in_bf = x_bf + (size_t)M_ROWS * 512;
    __hip_bfloat16* w_out_bf = w_in_bf + (size_t)2 * DPROJP * 512;

    // 0) dtype conversions
    cvt_x_kernel<<<dim3(M_ROWS * 512 / 1024), 256, 0, stream>>>(x, x_bf);
    cvt_win_kernel<<<dim3(DPROJP * 512 / 1024, 2), 256, 0, stream>>>(f_in_w, b_in_w, w_in_bf);
    cvt_wout_kernel<<<dim3(512 * DINNER / 1024, 2), 256, 0, stream>>>(f_out_w, b_out_w, w_out_bf);

    // 1) in_proj (MFMA): zx[dir] = x @ in_w[dir]^T  (M=4096, N=4480pad, K=512)
    gemm_mfma<false><<<dim3(DPROJP / 128, M_ROWS / 128, 2), 256, 0, stream>>>(
        x_bf, nullptr, nullptr, 0,
        w_in_bf, (long long)DPROJP * 512,
        zx, (long long)M_ROWS * DPROJP, DPROJP,
        nullptr, 0, 512);

    // 2) conv + SiLU + exact-f32 dt/dA
    conv_dt_kernel<<<dim3(M_ROWS, 2), 256, 0, stream>>>(
        zx, x, f_in_w, b_in_w,
        f_conv_w, b_conv_w, f_conv_b, b_conv_b,
        f_dtbias, b_dtbias, f_Alog, b_Alog,
        xs, Bcb, Ccb, dtb, dab);

    // 3a) segment-local scans (+ D-skip into y slice of zx)
    scan_seg_kernel<<<dim3(64 * NSEG, 2), 512, 0, stream>>>(
        xs, Bcb, Ccb, dtb, dab, f_D, b_D, zx, stateC, betac);

    // 3b) combine segment states
    combine_kernel<<<dim3(64, 2), 512, 0, stream>>>(stateC, betac);

    // 3c) inter-segment correction
    correct_kernel<<<dim3(64 * NSEG, 2), 512, 0, stream>>>(Ccb, betac, stateC, zx);

    // 4) gate + RMSNorm in place on y slice
    gatenorm_kernel<<<dim3(M_ROWS, 2), 256, 0, stream>>>(zx, f_nw, b_nw);

    // 5) out_proj (MFMA) + residual + concat  (M=4096, N=512, K=2048)
    gemm_mfma<true><<<dim3(512 / 128, M_ROWS / 128, 2), 256, 0, stream>>>(
        nullptr, zx + DINNER, zx + (size_t)M_ROWS * DPROJP + DINNER, DPROJP,
        w_out_bf, (long long)512 * DINNER,
        (float*)d_out, 512, 1024,
        x, 512, DINNER);
}

// Round 5
// 796.492 us; speedup vs baseline: 3.5900x; 1.3566x over previous
//
#include <hip/hip_runtime.h>
#include <hip/hip_bf16.h>
#include <math.h>

#define L_SEQ   2048
#define M_ROWS  4096            // B*L
#define DPROJ   4384
#define DPROJP  4480            // padded to 35*128 for MFMA GEMM
#define DINNER  2048
#define CONVDIM 2304
#define NST     128
#define NH      32
#define SEGLEN  256
#define NSEG    8
#define SC      8               // scan sub-chunk (steps per LDS stage)

typedef __attribute__((ext_vector_type(8))) short short8;
typedef __attribute__((ext_vector_type(4))) float f32x4;

union bf8u { short8 v; __hip_bfloat16 e[8]; };

// ---------------------------------------------------------------------------
// f32 -> bf16 conversion pre-passes
// ---------------------------------------------------------------------------
__global__ __launch_bounds__(256) void cvt_x_kernel(
    const float* __restrict__ x, __hip_bfloat16* __restrict__ xbf)
{
    const int i = (blockIdx.x * 256 + threadIdx.x) * 4;
    const float4 v = *(const float4*)(x + i);
    xbf[i + 0] = __float2bfloat16(v.x);
    xbf[i + 1] = __float2bfloat16(v.y);
    xbf[i + 2] = __float2bfloat16(v.z);
    xbf[i + 3] = __float2bfloat16(v.w);
}

__global__ __launch_bounds__(256) void cvt_win_kernel(
    const float* __restrict__ w0, const float* __restrict__ w1,
    __hip_bfloat16* __restrict__ dst)
{
    const int dir = blockIdx.y;
    const float* __restrict__ w = dir ? w1 : w0;
    __hip_bfloat16* __restrict__ d = dst + (size_t)dir * DPROJP * 512;
    const int i = (blockIdx.x * 256 + threadIdx.x) * 4;
    const int row = i >> 9;
    if (row < DPROJ) {
        const float4 v = *(const float4*)(w + i);
        d[i + 0] = __float2bfloat16(v.x);
        d[i + 1] = __float2bfloat16(v.y);
        d[i + 2] = __float2bfloat16(v.z);
        d[i + 3] = __float2bfloat16(v.w);
    } else {
        d[i + 0] = __float2bfloat16(0.f); d[i + 1] = __float2bfloat16(0.f);
        d[i + 2] = __float2bfloat16(0.f); d[i + 3] = __float2bfloat16(0.f);
    }
}

__global__ __launch_bounds__(256) void cvt_wout_kernel(
    const float* __restrict__ w0, const float* __restrict__ w1,
    __hip_bfloat16* __restrict__ dst)
{
    const int dir = blockIdx.y;
    const float* __restrict__ w = dir ? w1 : w0;
    __hip_bfloat16* __restrict__ d = dst + (size_t)dir * 512 * DINNER;
    const int i = (blockIdx.x * 256 + threadIdx.x) * 4;
    const float4 v = *(const float4*)(w + i);
    d[i + 0] = __float2bfloat16(v.x);
    d[i + 1] = __float2bfloat16(v.y);
    d[i + 2] = __float2bfloat16(v.z);
    d[i + 3] = __float2bfloat16(v.w);
}

// ---------------------------------------------------------------------------
// MFMA bf16 GEMM: C[M][N] = A[M][K] @ B[N][K]^T (+ optional f32 addsrc).
// 128x128 tile, BK=64, 256 threads (4 waves, 4x4 frags of 16x16x32).
// LDS XOR-swizzled for conflict-free ds_read_b128.
// ---------------------------------------------------------------------------
template<bool AF32>
__global__ __launch_bounds__(256) void gemm_mfma(
    const __hip_bfloat16* __restrict__ Abf,
    const float* __restrict__ Af0, const float* __restrict__ Af1, int lda_f,
    const __hip_bfloat16* __restrict__ Bw, long long b_dir_off,
    float* __restrict__ C, long long c_dir_off, int ldc,
    const float* __restrict__ addsrc, int add_ld,
    int K)
{
    const int dir = blockIdx.z;
    const int m0 = blockIdx.y * 128;
    const int n0 = blockIdx.x * 128;
    const __hip_bfloat16* __restrict__ B = Bw + (size_t)dir * b_dir_off;
    const float* __restrict__ Af = dir ? Af1 : Af0;
    float* __restrict__ Cp = C + (size_t)dir * c_dir_off;

    __shared__ __hip_bfloat16 Asl[128 * 64];
    __shared__ __hip_bfloat16 Bsl[128 * 64];

    const int tid  = threadIdx.x;
    const int lane = tid & 63;
    const int wid  = tid >> 6;
    const int wr   = (wid >> 1) << 6;
    const int wc   = (wid & 1) << 6;
    const int l15  = lane & 15;
    const int l4   = lane >> 4;

    f32x4 acc[4][4];
#pragma unroll
    for (int m = 0; m < 4; ++m)
#pragma unroll
        for (int n = 0; n < 4; ++n) acc[m][n] = (f32x4)0.f;

    for (int k0 = 0; k0 < K; k0 += 64) {
        __syncthreads();
#pragma unroll
        for (int i = 0; i < 4; ++i) {
            const int c    = tid + (i << 8);
            const int row  = c >> 3;
            const int slot = c & 7;
            const int dst  = (row << 7) + ((slot ^ (row & 7)) << 4);
            if (AF32) {
                const float* s = Af + (size_t)(m0 + row) * lda_f + k0 + (slot << 3);
                const float4 lo = *(const float4*)(s);
                const float4 hi = *(const float4*)(s + 4);
                bf8u u;
                u.e[0] = __float2bfloat16(lo.x); u.e[1] = __float2bfloat16(lo.y);
                u.e[2] = __float2bfloat16(lo.z); u.e[3] = __float2bfloat16(lo.w);
                u.e[4] = __float2bfloat16(hi.x); u.e[5] = __float2bfloat16(hi.y);
                u.e[6] = __float2bfloat16(hi.z); u.e[7] = __float2bfloat16(hi.w);
                *(short8*)((char*)Asl + dst) = u.v;
            } else {
                *(short8*)((char*)Asl + dst) =
                    *(const short8*)(Abf + (size_t)(m0 + row) * K + k0 + (slot << 3));
            }
            *(short8*)((char*)Bsl + dst) =
                *(const short8*)(B + (size_t)(n0 + row) * K + k0 + (slot << 3));
        }
        __syncthreads();

#pragma unroll
        for (int kh = 0; kh < 2; ++kh) {
            const int ks = (kh << 2) + l4;
            short8 a[4], b[4];
#pragma unroll
            for (int m = 0; m < 4; ++m) {
                const int R = wr + (m << 4) + l15;
                a[m] = *(const short8*)((const char*)Asl + (R << 7) + ((ks ^ (R & 7)) << 4));
            }
#pragma unroll
            for (int n = 0; n < 4; ++n) {
                const int R = wc + (n << 4) + l15;
                b[n] = *(const short8*)((const char*)Bsl + (R << 7) + ((ks ^ (R & 7)) << 4));
            }
#pragma unroll
            for (int m = 0; m < 4; ++m)
#pragma unroll
                for (int n = 0; n < 4; ++n)
                    acc[m][n] = __builtin_amdgcn_mfma_f32_16x16x32_bf16(
                        a[m], b[n], acc[m][n], 0, 0, 0);
        }
    }

#pragma unroll
    for (int m = 0; m < 4; ++m) {
        const int row0 = m0 + wr + (m << 4) + (l4 << 2);
#pragma unroll
        for (int n = 0; n < 4; ++n) {
            const int col = n0 + wc + (n << 4) + l15;
#pragma unroll
            for (int r = 0; r < 4; ++r) {
                float v = acc[m][n][r];
                if (addsrc) v += addsrc[(size_t)(row0 + r) * add_ld + col];
                Cp[(size_t)(row0 + r) * ldc + col] = v;
            }
        }
    }
}

// ---------------------------------------------------------------------------
// Depthwise causal conv(4) + SiLU; dt recomputed exactly in f32; softplus;
// dA = exp(dt * -exp(A_log)). Bwd = tap reversal at original index.
// ---------------------------------------------------------------------------
__global__ __launch_bounds__(256) void conv_dt_kernel(
    const float* __restrict__ zx, const float* __restrict__ x,
    const float* __restrict__ inw0, const float* __restrict__ inw1,
    const float* __restrict__ cw0, const float* __restrict__ cw1,
    const float* __restrict__ cb0, const float* __restrict__ cb1,
    const float* __restrict__ dtbias0, const float* __restrict__ dtbias1,
    const float* __restrict__ Alog0, const float* __restrict__ Alog1,
    __hip_bfloat16* __restrict__ xs, float* __restrict__ Bcb, float* __restrict__ Ccb,
    float* __restrict__ dtb, float* __restrict__ dab)
{
    const int dir = blockIdx.y;
    const int row = blockIdx.x;
    const int b = row >> 11;
    const int l = row & (L_SEQ - 1);

    const float* __restrict__ cw = dir ? cw1 : cw0;
    const float* __restrict__ cb = dir ? cb1 : cb0;
    const float* __restrict__ zbase = zx + (size_t)dir * M_ROWS * DPROJP;
    const size_t orow = (size_t)(dir * M_ROWS + row);

    for (int c = threadIdx.x; c < CONVDIM; c += 256) {
        float acc = cb[c];
        const float w0 = cw[c * 4 + 0], w1 = cw[c * 4 + 1];
        const float w2 = cw[c * 4 + 2], w3 = cw[c * 4 + 3];
        if (dir == 0) {
#pragma unroll
            for (int k = 0; k < 4; ++k) {
                const int p = l - 3 + k;
                if (p >= 0) {
                    const float wv = (k == 0) ? w0 : (k == 1) ? w1 : (k == 2) ? w2 : w3;
                    acc += zbase[(size_t)(b * L_SEQ + p) * DPROJP + DINNER + c] * wv;
                }
            }
        } else {
#pragma unroll
            for (int k = 0; k < 4; ++k) {
                const int p = l + 3 - k;
                if (p < L_SEQ) {
                    const float wv = (k == 0) ? w0 : (k == 1) ? w1 : (k == 2) ? w2 : w3;
                    acc += zbase[(size_t)(b * L_SEQ + p) * DPROJP + DINNER + c] * wv;
                }
            }
        }
        const float s = acc / (1.f + expf(-acc));
        if (c < DINNER)            xs[orow * DINNER + c] = __float2bfloat16(s);
        else if (c < DINNER + NST) Bcb[orow * NST + (c - DINNER)] = s;
        else                       Ccb[orow * NST + (c - DINNER - NST)] = s;
    }

    {
        const int h = threadIdx.x >> 3;
        const int part = threadIdx.x & 7;
        const float* __restrict__ xr = x + (size_t)row * 512 + part * 64;
        const float* __restrict__ wr_ = (dir ? inw1 : inw0)
            + (size_t)(DINNER + CONVDIM + h) * 512 + part * 64;
        float s = 0.f;
#pragma unroll
        for (int k = 0; k < 64; ++k) s = fmaf(xr[k], wr_[k], s);
        s += __shfl_xor(s, 1);
        s += __shfl_xor(s, 2);
        s += __shfl_xor(s, 4);
        if (part == 0) {
            const float v = s + (dir ? dtbias1 : dtbias0)[h];
            const float sp = (v > 20.f) ? v : log1pf(expf(v));
            const float a = -expf((dir ? Alog1 : Alog0)[h]);
            dtb[orow * NH + h] = sp;
            dab[orow * NH + h] = expf(sp * a);
        }
    }
}

// ---------------------------------------------------------------------------
// Pass A: segment-local scan, SC-step sub-chunk staged, double-buffered LDS,
// 1 barrier per SC steps. Roles: tid<64 x | <192 B | <320 C | <336 dt/dA.
// ---------------------------------------------------------------------------
__global__ __launch_bounds__(512) void scan_seg_kernel(
    const __hip_bfloat16* __restrict__ xs, const float* __restrict__ Bcb,
    const float* __restrict__ Ccb, const float* __restrict__ dtb,
    const float* __restrict__ dab,
    const float* __restrict__ D0, const float* __restrict__ D1,
    float* __restrict__ zx, __hip_bfloat16* __restrict__ stateC,
    float* __restrict__ betac)
{
    const int dir = blockIdx.y;
    const int bx  = blockIdx.x;
    const int bh  = bx >> 3;
    const int seg = bx & 7;
    const int b = bh >> 5, h = bh & 31;
    const int tid = threadIdx.x;
    const int p = tid >> 3;
    const int g = tid & 7;
    const float Dv = (dir ? D1 : D0)[h];
    const int base_bh = (dir * 2 + b) * 32 + h;
    const int t0 = seg * SEGLEN;

    __shared__ float sx[2][SC][64];
    __shared__ float sB[2][SC][8][20];
    __shared__ float sC[2][SC][8][20];
    __shared__ float sS[2][SC][2];

    float hst[16];
#pragma unroll
    for (int i = 0; i < 16; ++i) hst[i] = 0.f;
    float beta = 1.f;

    const size_t dbase = (size_t)(dir * M_ROWS + b * L_SEQ);
    float* __restrict__ ybase = zx + (size_t)dir * M_ROWS * DPROJP + DINNER;

    // prologue: stage sub-chunk 0 into buf 0
    if (tid < 64) {
#pragma unroll
        for (int s = 0; s < SC; ++s) {
            const int t = t0 + s;
            const int l = dir ? (L_SEQ - 1 - t) : t;
            sx[0][s][tid] = __bfloat162float(xs[(dbase + l) * DINNER + h * 64 + tid]);
        }
    } else if (tid < 192) {
        const int n = tid - 64;
#pragma unroll
        for (int s = 0; s < SC; ++s) {
            const int t = t0 + s;
            const int l = dir ? (L_SEQ - 1 - t) : t;
            sB[0][s][n >> 4][n & 15] = Bcb[(dbase + l) * NST + n];
        }
    } else if (tid < 320) {
        const int n = tid - 192;
#pragma unroll
        for (int s = 0; s < SC; ++s) {
            const int t = t0 + s;
            const int l = dir ? (L_SEQ - 1 - t) : t;
            sC[0][s][n >> 4][n & 15] = Ccb[(dbase + l) * NST + n];
        }
    } else if (tid < 336) {
        const int q = tid - 320;
        const int s = q >> 1;
        const int t = t0 + s;
        const int l = dir ? (L_SEQ - 1 - t) : t;
        sS[0][s][q & 1] = ((q & 1) ? dab : dtb)[(dbase + l) * NH + h];
    }
    __syncthreads();

    const int NC = SEGLEN / SC;
    for (int c = 0; c < NC; ++c) {
        const int cur = c & 1, nxt = cur ^ 1;
        const bool have = (c + 1 < NC);
        float pv[SC];

        // issue next sub-chunk's global loads into registers
        if (have) {
            const int tb = t0 + (c + 1) * SC;
            if (tid < 64) {
#pragma unroll
                for (int s = 0; s < SC; ++s) {
                    const int l = dir ? (L_SEQ - 1 - (tb + s)) : (tb + s);
                    pv[s] = __bfloat162float(xs[(dbase + l) * DINNER + h * 64 + tid]);
                }
            } else if (tid < 192) {
                const int n = tid - 64;
#pragma unroll
                for (int s = 0; s < SC; ++s) {
                    const int l = dir ? (L_SEQ - 1 - (tb + s)) : (tb + s);
                    pv[s] = Bcb[(dbase + l) * NST + n];
                }
            } else if (tid < 320) {
                const int n = tid - 192;
#pragma unroll
                for (int s = 0; s < SC; ++s) {
                    const int l = dir ? (L_SEQ - 1 - (tb + s)) : (tb + s);
                    pv[s] = Ccb[(dbase + l) * NST + n];
                }
            } else if (tid < 336) {
                const int q = tid - 320;
                const int s = q >> 1;
                const int l = dir ? (L_SEQ - 1 - (tb + s)) : (tb + s);
                pv[0] = ((q & 1) ? dab : dtb)[(dbase + l) * NH + h];
            }
        }

        // compute SC steps from buf cur (no per-step barrier)
#pragma unroll
        for (int s = 0; s < SC; ++s) {
            const int t = t0 + c * SC + s;
            const float dtv = sS[cur][s][0];
            const float dav = sS[cur][s][1];
            const float xv  = sx[cur][s][p];
            const float sxv = dtv * xv;
            const float4* __restrict__ Bp4 = (const float4*)sB[cur][s][g];
            const float4* __restrict__ Cp4 = (const float4*)sC[cur][s][g];
            float acc0 = 0.f, acc1 = 0.f;
#pragma unroll
            for (int q4 = 0; q4 < 4; ++q4) {
                const float4 bv = Bp4[q4];
                const float4 cv = Cp4[q4];
                float* hj = &hst[q4 * 4];
                hj[0] = fmaf(hj[0], dav, sxv * bv.x); acc0 = fmaf(hj[0], cv.x, acc0);
                hj[1] = fmaf(hj[1], dav, sxv * bv.y); acc1 = fmaf(hj[1], cv.y, acc1);
                hj[2] = fmaf(hj[2], dav, sxv * bv.z); acc0 = fmaf(hj[2], cv.z, acc0);
                hj[3] = fmaf(hj[3], dav, sxv * bv.w); acc1 = fmaf(hj[3], cv.w, acc1);
            }
            float acc = acc0 + acc1;
            acc += __shfl_xor(acc, 1);
            acc += __shfl_xor(acc, 2);
            acc += __shfl_xor(acc, 4);
            beta *= dav;
            if (tid == 0) betac[(size_t)base_bh * L_SEQ + t] = beta;
            if (g == 0) {
                const int l = dir ? (L_SEQ - 1 - t) : t;
                ybase[(size_t)(b * L_SEQ + l) * DPROJP + h * 64 + p] = acc + Dv * xv;
            }
        }

        // write prefetched regs into the other buffer
        if (have) {
            if (tid < 64) {
#pragma unroll
                for (int s = 0; s < SC; ++s) sx[nxt][s][tid] = pv[s];
            } else if (tid < 192) {
                const int n = tid - 64;
#pragma unroll
                for (int s = 0; s < SC; ++s) sB[nxt][s][n >> 4][n & 15] = pv[s];
            } else if (tid < 320) {
                const int n = tid - 192;
#pragma unroll
                for (int s = 0; s < SC; ++s) sC[nxt][s][n >> 4][n & 15] = pv[s];
            } else if (tid < 336) {
                const int q = tid - 320;
                sS[nxt][q >> 1][q & 1] = pv[0];
            }
        }
        __syncthreads();
    }

    const size_t soff = ((size_t)(base_bh * NSEG + seg)) * 8192 + (size_t)tid * 16;
#pragma unroll
    for (int j = 0; j < 16; ++j)
        stateC[soff + j] = __float2bfloat16(hst[j]);
}

// ---------------------------------------------------------------------------
// Pass B: sequential combine over segments (in place).
// ---------------------------------------------------------------------------
__global__ __launch_bounds__(512) void combine_kernel(
    __hip_bfloat16* __restrict__ stateC, const float* __restrict__ betac)
{
    const int dir = blockIdx.y;
    const int bh  = blockIdx.x;
    const int base_bh = (dir * 2 + (bh >> 5)) * 32 + (bh & 31);
    const int tid = threadIdx.x;

    float hrun[16];
#pragma unroll
    for (int j = 0; j < 16; ++j) hrun[j] = 0.f;

    for (int s = 0; s < NSEG; ++s) {
        const size_t off = ((size_t)(base_bh * NSEG + s)) * 8192 + (size_t)tid * 16;
        float c[16];
#pragma unroll
        for (int j = 0; j < 16; ++j) c[j] = __bfloat162float(stateC[off + j]);
#pragma unroll
        for (int j = 0; j < 16; ++j) stateC[off + j] = __float2bfloat16(hrun[j]);
        const float alpha = betac[(size_t)base_bh * L_SEQ + s * SEGLEN + (SEGLEN - 1)];
#pragma unroll
        for (int j = 0; j < 16; ++j) hrun[j] = fmaf(alpha, hrun[j], c[j]);
    }
}

// ---------------------------------------------------------------------------
// Pass C: y_t += betac[t] * (C_t . h_in[p,:]). SC-step staged like Pass A.
// ---------------------------------------------------------------------------
__global__ __launch_bounds__(512) void correct_kernel(
    const float* __restrict__ Ccb, const float* __restrict__ betac,
    const __hip_bfloat16* __restrict__ stateC, float* __restrict__ zx)
{
    const int dir = blockIdx.y;
    const int bx  = blockIdx.x;
    const int bh  = bx >> 3;
    const int seg = bx & 7;
    if (seg == 0) return;
    const int b = bh >> 5, h = bh & 31;
    const int tid = threadIdx.x;
    const int p = tid >> 3;
    const int g = tid & 7;
    const int base_bh = (dir * 2 + b) * 32 + h;
    const int t0 = seg * SEGLEN;

    float hin[16];
    {
        const size_t off = ((size_t)(base_bh * NSEG + seg)) * 8192 + (size_t)tid * 16;
#pragma unroll
        for (int j = 0; j < 16; ++j) hin[j] = __bfloat162float(stateC[off + j]);
    }

    __shared__ float sCt[2][SC][8][20];
    __shared__ float sbet[2][SC];

    const size_t dbase = (size_t)(dir * M_ROWS + b * L_SEQ);
    float* __restrict__ ybase = zx + (size_t)dir * M_ROWS * DPROJP + DINNER;

    // prologue
    if (tid < 128) {
#pragma unroll
        for (int s = 0; s < SC; ++s) {
            const int t = t0 + s;
            const int l = dir ? (L_SEQ - 1 - t) : t;
            sCt[0][s][tid >> 4][tid & 15] = Ccb[(dbase + l) * NST + tid];
        }
    } else if (tid < 136) {
        const int s = tid - 128;
        sbet[0][s] = betac[(size_t)base_bh * L_SEQ + t0 + s];
    }
    __syncthreads();

    const int NC = SEGLEN / SC;
    for (int c = 0; c < NC; ++c) {
        const int cur = c & 1, nxt = cur ^ 1;
        const bool have = (c + 1 < NC);
        float pv[SC];

        if (have) {
            const int tb = t0 + (c + 1) * SC;
            if (tid < 128) {
#pragma unroll
                for (int s = 0; s < SC; ++s) {
                    const int l = dir ? (L_SEQ - 1 - (tb + s)) : (tb + s);
                    pv[s] = Ccb[(dbase + l) * NST + tid];
                }
            } else if (tid < 136) {
                pv[0] = betac[(size_t)base_bh * L_SEQ + tb + (tid - 128)];
            }
        }

#pragma unroll
        for (int s = 0; s < SC; ++s) {
            const int t = t0 + c * SC + s;
            const float4* __restrict__ Cp4 = (const float4*)sCt[cur][s][g];
            float acc0 = 0.f, acc1 = 0.f;
#pragma unroll
            for (int q4 = 0; q4 < 4; ++q4) {
                const float4 cv = Cp4[q4];
                const float* hj = &hin[q4 * 4];
                acc0 = fmaf(hj[0], cv.x, acc0);
                acc1 = fmaf(hj[1], cv.y, acc1);
                acc0 = fmaf(hj[2], cv.z, acc0);
                acc1 = fmaf(hj[3], cv.w, acc1);
            }
            float acc = acc0 + acc1;
            acc += __shfl_xor(acc, 1);
            acc += __shfl_xor(acc, 2);
            acc += __shfl_xor(acc, 4);
            if (g == 0) {
                const int l = dir ? (L_SEQ - 1 - t) : t;
                ybase[(size_t)(b * L_SEQ + l) * DPROJP + h * 64 + p] += sbet[cur][s] * acc;
            }
        }

        if (have) {
            if (tid < 128) {
#pragma unroll
                for (int s = 0; s < SC; ++s) sCt[nxt][s][tid >> 4][tid & 15] = pv[s];
            } else if (tid < 136) {
                sbet[nxt][tid - 128] = pv[0];
            }
        }
        __syncthreads();
    }
}

// ---------------------------------------------------------------------------
// y = y * silu(z); RMSNorm(2048) * norm_w, in place on y slice of zx.
// ---------------------------------------------------------------------------
__global__ __launch_bounds__(256) void gatenorm_kernel(
    float* __restrict__ zx,
    const float* __restrict__ nw0, const float* __restrict__ nw1)
{
    const int dir = blockIdx.y;
    const int row = blockIdx.x;
    const float* __restrict__ nw = dir ? nw1 : nw0;
    float* __restrict__ rowp = zx + (size_t)dir * M_ROWS * DPROJP + (size_t)row * DPROJP;
    const int tid = threadIdx.x;

    float gv[8];
    float ss = 0.f;
#pragma unroll
    for (int i = 0; i < 8; ++i) {
        const int c = i * 256 + tid;
        const float yv = rowp[DINNER + c];
        const float zv = rowp[c];
        const float gg = yv * (zv / (1.f + expf(-zv)));
        gv[i] = gg;
        ss = fmaf(gg, gg, ss);
    }
#pragma unroll
    for (int off = 1; off < 64; off <<= 1) ss += __shfl_xor(ss, off);
    __shared__ float red[4];
    if ((tid & 63) == 0) red[tid >> 6] = ss;
    __syncthreads();
    const float total = red[0] + red[1] + red[2] + red[3];
    const float rs = rsqrtf(total * (1.f / (float)DINNER) + 1e-5f);
#pragma unroll
    for (int i = 0; i < 8; ++i) {
        const int c = i * 256 + tid;
        rowp[DINNER + c] = gv[i] * rs * nw[c];
    }
}

// ---------------------------------------------------------------------------
extern "C" void kernel_launch(void* const* d_in, const int* in_sizes, int n_in,
                              void* d_out, int out_size, void* d_ws, size_t ws_size,
                              hipStream_t stream)
{
    (void)in_sizes; (void)n_in; (void)out_size; (void)ws_size;
    const float* x        = (const float*)d_in[0];
    const float* f_in_w   = (const float*)d_in[1];
    const float* f_conv_w = (const float*)d_in[2];
    const float* f_conv_b = (const float*)d_in[3];
    const float* f_dtbias = (const float*)d_in[4];
    const float* f_Alog   = (const float*)d_in[5];
    const float* f_D      = (const float*)d_in[6];
    const float* f_nw     = (const float*)d_in[7];
    const float* f_out_w  = (const float*)d_in[8];
    const float* b_in_w   = (const float*)d_in[9];
    const float* b_conv_w = (const float*)d_in[10];
    const float* b_conv_b = (const float*)d_in[11];
    const float* b_dtbias = (const float*)d_in[12];
    const float* b_Alog   = (const float*)d_in[13];
    const float* b_D      = (const float*)d_in[14];
    const float* b_nw     = (const float*)d_in[15];
    const float* b_out_w  = (const float*)d_in[16];

    float* ws  = (float*)d_ws;
    float* zx  = ws;
    __hip_bfloat16* xs = (__hip_bfloat16*)(zx + (size_t)2 * M_ROWS * DPROJP);
    float* Bcb = (float*)(xs + (size_t)2 * M_ROWS * DINNER);
    float* Ccb = Bcb + (size_t)2 * M_ROWS * NST;
    float* dtb = Ccb + (size_t)2 * M_ROWS * NST;
    float* dab = dtb + (size_t)2 * M_ROWS * NH;
    __hip_bfloat16* stateC = (__hip_bfloat16*)(dab + (size_t)2 * M_ROWS * NH);
    float* betac = (float*)(stateC + (size_t)128 * NSEG * 8192);
    __hip_bfloat16* x_bf    = (__hip_bfloat16*)(betac + (size_t)128 * L_SEQ);
    __hip_bfloat16* w_in_bf = x_bf + (size_t)M_ROWS * 512;
    __hip_bfloat16* w_out_bf = w_in_bf + (size_t)2 * DPROJP * 512;

    // 0) dtype conversions
    cvt_x_kernel<<<dim3(M_ROWS * 512 / 1024), 256, 0, stream>>>(x, x_bf);
    cvt_win_kernel<<<dim3(DPROJP * 512 / 1024, 2), 256, 0, stream>>>(f_in_w, b_in_w, w_in_bf);
    cvt_wout_kernel<<<dim3(512 * DINNER / 1024, 2), 256, 0, stream>>>(f_out_w, b_out_w, w_out_bf);

    // 1) in_proj (MFMA): zx[dir] = x @ in_w[dir]^T
    gemm_mfma<false><<<dim3(DPROJP / 128, M_ROWS / 128, 2), 256, 0, stream>>>(
        x_bf, nullptr, nullptr, 0,
        w_in_bf, (long long)DPROJP * 512,
        zx, (long long)M_ROWS * DPROJP, DPROJP,
        nullptr, 0, 512);

    // 2) conv + SiLU + exact-f32 dt/dA
    conv_dt_kernel<<<dim3(M_ROWS, 2), 256, 0, stream>>>(
        zx, x, f_in_w, b_in_w,
        f_conv_w, b_conv_w, f_conv_b, b_conv_b,
        f_dtbias, b_dtbias, f_Alog, b_Alog,
        xs, Bcb, Ccb, dtb, dab);

    // 3a) segment-local scans (+ D-skip into y slice of zx)
    scan_seg_kernel<<<dim3(64 * NSEG, 2), 512, 0, stream>>>(
        xs, Bcb, Ccb, dtb, dab, f_D, b_D, zx, stateC, betac);

    // 3b) combine segment states
    combine_kernel<<<dim3(64, 2), 512, 0, stream>>>(stateC, betac);

    // 3c) inter-segment correction
    correct_kernel<<<dim3(64 * NSEG, 2), 512, 0, stream>>>(Ccb, betac, stateC, zx);

    // 4) gate + RMSNorm in place on y slice
    gatenorm_kernel<<<dim3(M_ROWS, 2), 256, 0, stream>>>(zx, f_nw, b_nw);

    // 5) out_proj (MFMA) + residual + concat
    gemm_mfma<true><<<dim3(512 / 128, M_ROWS / 128, 2), 256, 0, stream>>>(
        nullptr, zx + DINNER, zx + (size_t)M_ROWS * DPROJP + DINNER, DPROJP,
        w_out_bf, (long long)512 * DINNER,
        (float*)d_out, 512, 1024,
        x, 512, DINNER);
}